// Round 7
// baseline (52.924 us; speedup 1.0000x reference)
//
#include <hip/hip_runtime.h>
#include <math.h>

#define EPS_F 1e-6f
#define CLIP_HI 0.999999f
#define IMG_W 224
#define IMG_H 224
#define ROWF (IMG_W * 3)   // 672 floats per (b,h) row; 672 % 4 == 0

typedef float f32x4 __attribute__((ext_vector_type(4)));
typedef float f32x4_u __attribute__((ext_vector_type(4), aligned(4)));  // dword-aligned vector load

__device__ __forceinline__ float clip01(float u) {
    return fminf(fmaxf(u, EPS_F), CLIP_HI);
}

// Each thread handles 8 output float4s spaced an eighth of the tensor apart.
// eighthN = out_size/8 = 7168 rows = 32 whole images, so all 8 positions share
// the same h and the same within-row offset -> ONE back-map chain serves all
// 8 loads/stores, and 8 independent dwordx4 loads are in flight per thread.
__global__ __launch_bounds__(256) void warp_kernel(const float* __restrict__ x,
                                                   const float* __restrict__ spw,
                                                   const float* __restrict__ spp,
                                                   const float* __restrict__ spm,
                                                   const float* __restrict__ ug,
                                                   const float* __restrict__ ul,
                                                   float* __restrict__ out,
                                                   int eighthN) {
    __shared__ float sdec[8];   // [a0,b0,m0,_, a1,b1,m1,_] (a,b = 0 when inactive)
    if (threadIdx.x == 0) {
#pragma unroll
        for (int i = 0; i < 2; ++i) {
            float g0 = -logf(-logf(clip01(ug[i * 2 + 0])));
            float g1 = -logf(-logf(clip01(ug[i * 2 + 1])));
            int j = (spw[i * 2 + 0] + g0 >= spw[i * 2 + 1] + g1) ? 0 : 1;
            float p = clip01(spp[i * 2 + j]);
            float uc = clip01(ul[i * 2 + j]);
            float l = logf(uc) - log1pf(-uc);
            float s = (logf(p) - log1pf(-p)) + l;   // tau = 1
            float y = 1.0f / (1.0f + expf(-s));
            int hw = (int)rintf(y);
            float m = spm[i * 2 + j];
            float a = 0.f, b = 0.f;
            if (hw == 1) {
                if (j == 0) a = 0.6f * m - 0.3f;          // shear_x
                else        b = -(20.0f * m - 10.0f);     // translate_x
            }
            sdec[i * 4 + 0] = a;
            sdec[i * 4 + 1] = b;
            sdec[i * 4 + 2] = m;
            sdec[i * 4 + 3] = 0.f;
        }
    }
    __syncthreads();
    const float a0 = sdec[0], b0 = sdec[1], m0 = sdec[2];
    const float a1 = sdec[4], b1 = sdec[5], m1 = sdec[6];

    int q = blockIdx.x * 256 + threadIdx.x;
    int pos = q * 4;                  // float index within the first eighth
    int row = pos / ROWF;
    int within = pos - row * ROWF;
    int h = row % IMG_H;
    int base = row * ROWF;
    const float hf = (float)h;
    const float sh1 = a1 * hf + b1;   // stage applied second -> inverted first
    const float sh0 = a0 * hf + b0;   // stage applied first

    int wA = within / 3;
    int cA = within - wA * 3;

    // shared back-map chain (identical for all 8 eighth-streams)
    int x1A = (int)rintf((float)wA + sh1);
    bool vA = (x1A >= 0) && (x1A < IMG_W);
    int x0A = (int)rintf((float)x1A + sh0);
    vA = vA && (x0A >= 0) && (x0A < IMG_W);

    int x1B = (int)rintf((float)(wA + 1) + sh1);
    bool vB = (x1B >= 0) && (x1B < IMG_W);
    int x0B = (int)rintf((float)x1B + sh0);
    vB = vB && (x0B >= 0) && (x0B < IMG_W);

    bool fast = vA && vB && (x0B == x0A + 1);

    f32x4 o[8];
    if (__all(fast)) {
        int srcoff = base + 3 * x0A + cA;       // contiguous 4-float source
        f32x4_u v[8];
#pragma unroll
        for (int k = 0; k < 8; ++k)             // 8 loads issued back-to-back
            v[k] = *reinterpret_cast<const f32x4_u*>(&x[srcoff + k * eighthN]);
#pragma unroll
        for (int k = 0; k < 8; ++k)
#pragma unroll
            for (int e = 0; e < 4; ++e)
                o[k][e] = (((v[k][e] + m0) - m0) + m1) - m1;   // fp-exact nudge
    } else {
        int offs[4];
        bool vs[4];
#pragma unroll
        for (int e = 0; e < 4; ++e) {
            int ce = cA + e;
            bool useB = (ce >= 3);
            int w0 = useB ? x0B : x0A;
            bool v = useB ? vB : vA;
            int cc = useB ? (ce - 3) : ce;
            int w0c = min(max(w0, 0), IMG_W - 1);
            offs[e] = base + 3 * w0c + cc;
            vs[e] = v;
        }
#pragma unroll
        for (int k = 0; k < 8; ++k) {
            float vals[4];
#pragma unroll
            for (int e = 0; e < 4; ++e) vals[e] = x[offs[e] + k * eighthN];
#pragma unroll
            for (int e = 0; e < 4; ++e) {
                float t = vs[e] ? vals[e] : 0.f;
                t = (((t + m0) - m0) + m1) - m1;
                o[k][e] = vs[e] ? t : 0.f;
            }
        }
    }

#pragma unroll
    for (int k = 0; k < 8; ++k)
        __builtin_nontemporal_store(o[k], reinterpret_cast<f32x4*>(&out[pos + k * eighthN]));
}

extern "C" void kernel_launch(void* const* d_in, const int* in_sizes, int n_in,
                              void* d_out, int out_size, void* d_ws, size_t ws_size,
                              hipStream_t stream) {
    const float* x   = (const float*)d_in[0];
    const float* spw = (const float*)d_in[1];
    const float* spp = (const float*)d_in[2];
    const float* spm = (const float*)d_in[3];
    const float* ug  = (const float*)d_in[4];
    const float* ul  = (const float*)d_in[5];
    float* out = (float*)d_out;

    int eighthN = out_size / 8;                 // 7168 whole rows = 32 images
    int threads = eighthN / 4;                  // one float4 per stream
    int blocks = threads / 256;                 // exact: 4704
    warp_kernel<<<blocks, 256, 0, stream>>>(x, spw, spp, spm, ug, ul, out, eighthN);
}